// Round 8
// baseline (747.555 us; speedup 1.0000x reference)
//
#include <hip/hip_runtime.h>
#include <hip/hip_bf16.h>

// Attention: B=2, S=2048, D=2048, NH=32, NKV=8, HD=64, causal, RoPE, GQA.
// Inputs fp32, OUTPUT fp32. Internal bf16 MFMA, fp32 accumulate.
//
// ws layout (63 MB, bf16 elems):
//   xb/Obuf :  8,388,608 (4096x2048) — xb dead after QKV GEMM, reused as Obuf
//   qkv     : 12,582,912 (4096x3072)
//   woT     :  4,194,304 (2048x2048)
//   wqkvT/Vt:  6,291,456 — wqkvT dead after QKV GEMM, reused as Vt[b*8+kh][64][2048]
//
// Pipeline (5 launches): prep (cast + 4x weight-transpose) -> QKV GEMM ->
// rope+vtrans (all 40 heads roped, Q pre-scaled; V transposed) -> flash10 ->
// out-proj GEMM (128x128).

#define S_LEN 2048
#define BATCH 2
#define D_MODEL 2048
#define NH 32
#define NKV 8
#define HD 64
#define KV_D (NKV * HD)            // 512
#define QKV_N (D_MODEL + 2 * KV_D) // 3072

typedef __attribute__((ext_vector_type(8))) short short8;
typedef __attribute__((ext_vector_type(4))) float float4v;
typedef __attribute__((ext_vector_type(16))) float f32x16;
typedef __attribute__((ext_vector_type(2))) unsigned uint2v;

typedef __attribute__((address_space(1))) const unsigned int gu32;
typedef __attribute__((address_space(3))) unsigned int lu32;

// Q is pre-scaled by 0.125*log2(e) in rope; scores then feed v_exp_f32 (2^x) raw.
#if __has_builtin(__builtin_amdgcn_exp2f)
#define PEXP(x) __builtin_amdgcn_exp2f(x)
#else
#define PEXP(x) __expf((x) * 0.69314718f)
#endif
#define QSCALE 0.18033688f  // 0.125 * log2(e)

__device__ __forceinline__ float bf2f(unsigned short u) {
    unsigned x = ((unsigned)u) << 16;
    return __builtin_bit_cast(float, x);
}
__device__ __forceinline__ unsigned short f2bf(float f) {
    unsigned u = __builtin_bit_cast(unsigned, f);
    unsigned r = (u + 0x7fffu + ((u >> 16) & 1u)) >> 16;
    return (unsigned short)r;
}

// packed f32x2 -> bf16x2 (RNE), single instruction
__device__ __forceinline__ unsigned cvt_pk_bf16(float a, float b) {
    unsigned r;
    asm("v_cvt_pk_bf16_f32 %0, %1, %2" : "=v"(r) : "v"(a), "v"(b));
    return r;
}

// permlane32_swap(a, b) -> (x, y)
__device__ __forceinline__ void pl32swap(unsigned a, unsigned b,
                                         unsigned& x, unsigned& y) {
#if __has_builtin(__builtin_amdgcn_permlane32_swap)
    uint2v r = __builtin_amdgcn_permlane32_swap(a, b, false, false);
    x = r[0];
    y = r[1];
#else
    unsigned pa = (unsigned)__shfl_xor((int)a, 32);
    unsigned pb = (unsigned)__shfl_xor((int)b, 32);
    bool lo = (threadIdx.x & 63) < 32;
    x = lo ? a : pb;
    y = lo ? pa : b;
#endif
}

// ---- prep: fused {wq,wk,wv,wo transpose+cast} + {x fp32->bf16 cast}.
// Flat grid 18432 blocks: [0,4096) wq, [4096,5120) wk, [5120,6144) wv,
// [6144,10240) wo, [10240,18432) cast. All block-independent.
__global__ __launch_bounds__(256) void prep(const float* __restrict__ x,
                                            const float* __restrict__ wq,
                                            const float* __restrict__ wk,
                                            const float* __restrict__ wv,
                                            const float* __restrict__ wo,
                                            unsigned short* __restrict__ xb,
                                            unsigned short* __restrict__ wqkvT,
                                            unsigned short* __restrict__ woT) {
    __shared__ unsigned short t[32 * 33];
    const int bx = blockIdx.x;
    if (bx >= 10240) {  // elementwise cast, 4 elems/thread
        long i = ((long)(bx - 10240) * 256 + threadIdx.x) * 4;
        const long n = (long)BATCH * S_LEN * D_MODEL;
        if (i + 3 >= n) return;
        const float4v v = *(const float4v*)&x[i];
        unsigned short o[4];
        o[0] = f2bf(v[0]); o[1] = f2bf(v[1]); o[2] = f2bf(v[2]); o[3] = f2bf(v[3]);
        *(__attribute__((ext_vector_type(4))) short*)&xb[i] =
            *(__attribute__((ext_vector_type(4))) short*)o;
        return;
    }
    // weight transpose: out[n*K+k] = bf16(in[k*N+n]), K=2048 rows
    const float* in;
    unsigned short* out;
    int N, nb, kb;
    if (bx < 4096) {
        in = wq; out = wqkvT; N = 2048;
        nb = (bx & 63) * 32; kb = (bx >> 6) * 32;
    } else if (bx < 5120) {
        const int i2 = bx - 4096;
        in = wk; out = wqkvT + (long)D_MODEL * D_MODEL; N = 512;
        nb = (i2 & 15) * 32; kb = (i2 >> 4) * 32;
    } else if (bx < 6144) {
        const int i2 = bx - 5120;
        in = wv; out = wqkvT + (long)(D_MODEL + KV_D) * D_MODEL; N = 512;
        nb = (i2 & 15) * 32; kb = (i2 >> 4) * 32;
    } else {
        const int i2 = bx - 6144;
        in = wo; out = woT; N = 2048;
        nb = (i2 & 63) * 32; kb = (i2 >> 6) * 32;
    }
    const int c = threadIdx.x & 31, rr = threadIdx.x >> 5;
#pragma unroll
    for (int it = 0; it < 4; ++it) {
        int r = it * 8 + rr;
        t[c * 33 + r] = f2bf(in[(long)(kb + r) * N + nb + c]);
    }
    __syncthreads();
#pragma unroll
    for (int it = 0; it < 4; ++it) {
        int r = it * 8 + rr;
        out[(long)(nb + r) * D_MODEL + kb + c] = t[r * 33 + c];
    }
}

// GEMM: C(MxN) = A(MxK,bf16) * BT(NxK,bf16)^T, fp32/bf16 out.
// Tile TMx128, BK=64, global_load_lds(16) staging, XOR-swizzled LDS layout:
// row r's logical 16B chunk c stored at chunk (c ^ (r&7)) — conflict-free
// ds_read_b128 while keeping the DMA lane-contiguous.
template <int TM, bool F32OUT>
__global__ __launch_bounds__(256, TM == 64 ? 4 : 3)
void gemm_sw(const unsigned short* __restrict__ A,
             const unsigned short* __restrict__ BT,
             void* __restrict__ Cv, int M, int N, int K) {
    __shared__ unsigned short As[TM * 64];
    __shared__ unsigned short Bs[128 * 64];
    const int tid = threadIdx.x;
    const int wid = tid >> 6, lane = tid & 63;
    const int l15 = lane & 15, quad = lane >> 4;
    const int wm = (wid >> 1) * (TM / 2), wn = (wid & 1) * 64;
    const int row0 = blockIdx.x * TM, col0 = blockIdx.y * 128;
    constexpr int MI = TM / 32;  // m-frags per wave

    float4v acc[MI][4];
    float4v z;
    z[0] = z[1] = z[2] = z[3] = 0.0f;
    for (int mi = 0; mi < MI; ++mi)
        for (int ni = 0; ni < 4; ++ni) acc[mi][ni] = z;

    const int r_ld = lane >> 3;                          // 0..7 row in chunk16
    const int swz_ld = ((lane & 7) ^ (lane >> 3)) * 8;   // swizzled source col
    const int sw = l15 & 7;                              // read-side swizzle

    for (int kb = 0; kb < K; kb += 64) {
        __syncthreads();
#pragma unroll
        for (int c = 0; c < 4; ++c) {
            int chunk = c * 4 + wid;  // 16 chunks of 8 rows (B); TM/8 for A
            int r = chunk * 8 + r_ld;
            __builtin_amdgcn_global_load_lds(
                (gu32*)&BT[(long)(col0 + r) * K + kb + swz_ld],
                (lu32*)&Bs[chunk * 512], 16, 0, 0);
            if (c < MI)
                __builtin_amdgcn_global_load_lds(
                    (gu32*)&A[(long)(row0 + r) * K + kb + swz_ld],
                    (lu32*)&As[chunk * 512], 16, 0, 0);
        }
        __syncthreads();
#pragma unroll
        for (int kk = 0; kk < 64; kk += 32) {
            short8 af[MI], bf[4];
#pragma unroll
            for (int i = 0; i < MI; ++i)
                af[i] = *(const short8*)
                    &As[(wm + i * 16 + l15) * 64 + ((((kk >> 3) + quad) ^ sw) << 3)];
#pragma unroll
            for (int i = 0; i < 4; ++i)
                bf[i] = *(const short8*)
                    &Bs[(wn + i * 16 + l15) * 64 + ((((kk >> 3) + quad) ^ sw) << 3)];
#pragma unroll
            for (int mi = 0; mi < MI; ++mi)
#pragma unroll
                for (int ni = 0; ni < 4; ++ni)
                    acc[mi][ni] = __builtin_amdgcn_mfma_f32_16x16x32_bf16(
                        af[mi], bf[ni], acc[mi][ni], 0, 0, 0);
        }
    }
#pragma unroll
    for (int mi = 0; mi < MI; ++mi)
#pragma unroll
        for (int ni = 0; ni < 4; ++ni)
#pragma unroll
            for (int r = 0; r < 4; ++r) {
                int m = row0 + wm + mi * 16 + quad * 4 + r;
                int n = col0 + wn + ni * 16 + l15;
                if (F32OUT)
                    ((float*)Cv)[(long)m * N + n] = acc[mi][ni][r];
                else
                    ((unsigned short*)Cv)[(long)m * N + n] = f2bf(acc[mi][ni][r]);
            }
}

// ---- rope + vtrans, merged (independent regions of qkv).
// Blocks [0,512): RoPE all 40 heads (Q heads pre-scaled by QSCALE).
// Blocks [512,1024): V transpose qkv -> Vt[b*8+kh][64][2048].
__global__ __launch_bounds__(256) void rope_vtrans(unsigned short* __restrict__ qkv,
                                                   unsigned short* __restrict__ Vt) {
    __shared__ unsigned t[64 * 33];
    const int bx = blockIdx.x, tid = threadIdx.x;
    if (bx < 512) {
        const int i = tid & 31;
        const int row = bx * 8 + (tid >> 5);
        const int s = row & (S_LEN - 1);
        float freq = __expf(-0.28782313f * (float)i);  // 10000^(-i/32)
        float ang = (float)s * freq;
        float c = cosf(ang), sn = sinf(ang);
        unsigned* p = (unsigned*)qkv + ((long)row * QKV_N + 2 * i) / 2;
#pragma unroll
        for (int head = 0; head < 40; ++head) {
            const float qs = (head < 32) ? QSCALE : 1.0f;
            unsigned v = p[head * 32];
            float xr = bf2f((unsigned short)(v & 0xffff));
            float xi = bf2f((unsigned short)(v >> 16));
            unsigned short lo = f2bf((xr * c - xi * sn) * qs);
            unsigned short hi = f2bf((xr * sn + xi * c) * qs);
            p[head * 32] = (unsigned)lo | ((unsigned)hi << 16);
        }
        return;
    }
    const int idx = bx - 512;
    const int st = (idx & 31) * 64, kh = (idx >> 5) & 7, b = idx >> 8;
    {
        const int r2 = tid >> 3, dbase = (tid & 7) * 8;
        const unsigned short* src =
            qkv + ((long)(b * S_LEN + st + 2 * r2)) * QKV_N + D_MODEL + KV_D + kh * HD + dbase;
        short8 lo = *(const short8*)src;
        short8 hi = *(const short8*)(src + QKV_N);
#pragma unroll
        for (int j = 0; j < 8; ++j)
            t[(dbase + j) * 33 + r2] =
                (unsigned)(unsigned short)lo[j] | ((unsigned)(unsigned short)hi[j] << 16);
    }
    __syncthreads();
    {
        const int d = tid >> 2, sb = (tid & 3) * 8;
        unsigned short o[16];
#pragma unroll
        for (int jj = 0; jj < 8; ++jj) {
            unsigned v = t[d * 33 + sb + jj];
            o[2 * jj] = (unsigned short)(v & 0xffff);
            o[2 * jj + 1] = (unsigned short)(v >> 16);
        }
        unsigned short* dst =
            Vt + ((long)((b * 8 + kh) * 64 + d)) * S_LEN + st + sb * 2;
        *(short8*)dst = *(short8*)&o[0];
        *(short8*)(dst + 8) = *(short8*)&o[8];
    }
}

// Flash v10: 4-way parity at full wave occupancy. 1024-thr blocks, 16 waves:
// wave w = (g=w&3 q-group, p=w>>2 k-parity); parity p owns tiles t≡p (mod 4)
// in a CONSTANT buffer (buf=p, since (4ss+p)&3=p). Per superstep:
// stage own tile -> barrier (vmcnt drain) -> compute -> barrier. No prefetch
// (4 live + 4 next would need 128 KB); drain hidden by the co-resident block.
// LDS 68.6 KB -> 2 blocks/CU = 32 waves/CU (HW max; flash8 was 16).
// (qtA, 15-qtA) pairing -> UNIFORM 9 supersteps/block for every qtA.
// Valid because no running max (pure sum over tiles); 4 partials merged at
// epilogue via a 3-phase LDS tree overlaid on the dead K/V buffers.
// Inner math identical to flash8 (32x32 swapped-QK, in-register softmax via
// cvt_pk + permlane32_swap, PV as O^T = V^T P^T, XOR-swizzled LDS).
__global__ __launch_bounds__(1024, 8) void flash10(const unsigned short* __restrict__ qkv,
                                                   const unsigned short* __restrict__ Vt,
                                                   unsigned short* __restrict__ O) {
    __shared__ unsigned short SM[8 * 4096];  // K bufs at p*4096, V at 16384+p*4096
    __shared__ float mLs[768];               // lp relay for p=1,2,3

    const int tid = threadIdx.x, w = tid >> 6, lane = tid & 63;
    const int g = w & 3, p = w >> 2;
    const int l31 = lane & 31, hi = lane >> 5;
    const int r7 = l31 & 7;
    const int h = blockIdx.y, b = blockIdx.z;
    const int kh = h >> 2, bkh = b * 8 + kh;
    const int qtA = blockIdx.x;  // 0..7

    const int sr = lane >> 3;
    const int sc = ((lane & 7) ^ sr) * 8;
    const unsigned short* Kg =
        qkv + (long)b * S_LEN * QKV_N + D_MODEL + kh * HD + sc;
    const unsigned short* Vg = Vt + ((long)bkh * 64) * S_LEN + sc;
    unsigned short* const KB = &SM[p * 4096];
    unsigned short* const VB = &SM[16384 + p * 4096];

    for (int tsel = 0; tsel < 2; ++tsel) {
        const int qt = tsel ? (15 - qtA) : qtA;
        const int row_w = qt * 128 + g * 32;
        const int nkt = 2 * qt + 2;          // 64-key tiles
        const int nss = (nkt + 3) >> 2;      // supersteps (4 tiles each)

        // Q B-frags: lane holds col q = l31, d-rows ks*16 + hi*8 + 0..7
        short8 aq[4];
        {
            const long qbase = ((long)(b * S_LEN) + row_w + l31) * QKV_N + h * HD + hi * 8;
#pragma unroll
            for (int ks = 0; ks < 4; ++ks) aq[ks] = *(const short8*)&qkv[qbase + ks * 16];
        }

        f32x16 oacc[2] = {};
        float lp = 0.0f;

        for (int ss = 0; ss < nss; ++ss) {
            const int t = 4 * ss + p;
            const int k0 = t * 64;
            if (t < nkt) {  // stage this parity's tile into its own buffer
                const long kk0 = (long)t * 64;
                __builtin_amdgcn_global_load_lds(
                    (gu32*)&Kg[(kk0 + g * 16 + sr) * QKV_N],
                    (lu32*)&KB[(g * 16) * 64], 16, 0, 0);
                __builtin_amdgcn_global_load_lds(
                    (gu32*)&Kg[(kk0 + g * 16 + 8 + sr) * QKV_N],
                    (lu32*)&KB[(g * 16 + 8) * 64], 16, 0, 0);
                __builtin_amdgcn_global_load_lds(
                    (gu32*)&Vg[(long)(g * 16 + sr) * S_LEN + kk0],
                    (lu32*)&VB[(g * 16) * 64], 16, 0, 0);
                __builtin_amdgcn_global_load_lds(
                    (gu32*)&Vg[(long)(g * 16 + 8 + sr) * S_LEN + kk0],
                    (lu32*)&VB[(g * 16 + 8) * 64], 16, 0, 0);
            }
            __syncthreads();  // drain DMA; all parities' tiles ready

            if (t < nkt && row_w + 31 >= k0) {  // wave-level causal skip
                const bool mb = (k0 + 63 > row_w);
#pragma unroll
                for (int kb2 = 0; kb2 < 2; ++kb2) {
                    short8 kf[4];
#pragma unroll
                    for (int ks = 0; ks < 4; ++ks)
                        kf[ks] = *(const short8*)
                            &KB[(kb2 * 32 + l31) * 64 + (((ks * 2 + hi) ^ r7) << 3)];
                    f32x16 s = {};
                    __builtin_amdgcn_s_setprio(1);
#pragma unroll
                    for (int ks = 0; ks < 4; ++ks)
                        s = __builtin_amdgcn_mfma_f32_32x32x16_bf16(kf[ks], aq[ks], s, 0, 0, 0);
                    __builtin_amdgcn_s_setprio(0);

                    // s row = key = kb2*32 + (r&3)+8*(r>>2)+4*hi, col q = l31
                    const int qrel = row_w + l31 - k0 - kb2 * 32 - 4 * hi;
#pragma unroll
                    for (int r = 0; r < 16; ++r) {
                        float v = s[r];
                        if (mb && ((r & 3) + 8 * (r >> 2) > qrel)) v = -1e4f;
                        float pv = PEXP(v);
                        lp += pv;
                        s[r] = pv;
                    }

                    // P^T B-frags in-register (cvt_pk + permlane32_swap), then PV
#pragma unroll
                    for (int ksl = 0; ksl < 2; ++ksl) {
                        const int gx = ksl * 8;
                        unsigned ca = cvt_pk_bf16(s[gx + 0], s[gx + 1]);
                        unsigned cb = cvt_pk_bf16(s[gx + 2], s[gx + 3]);
                        unsigned cc = cvt_pk_bf16(s[gx + 4], s[gx + 5]);
                        unsigned cd = cvt_pk_bf16(s[gx + 6], s[gx + 7]);
                        unsigned dw0, dw1, dw2, dw3;
                        pl32swap(ca, cc, dw0, dw2);
                        pl32swap(cb, cd, dw1, dw3);
                        union { unsigned u[4]; short8 v8; } pf;
                        pf.u[0] = dw0; pf.u[1] = dw1; pf.u[2] = dw2; pf.u[3] = dw3;
                        const int lc = kb2 * 4 + ksl * 2 + hi;
                        __builtin_amdgcn_s_setprio(1);
#pragma unroll
                        for (int dblk = 0; dblk < 2; ++dblk) {
                            short8 vf = *(const short8*)
                                &VB[(dblk * 32 + l31) * 64 + ((lc ^ r7) << 3)];
                            oacc[dblk] = __builtin_amdgcn_mfma_f32_32x32x16_bf16(
                                vf, pf.v8, oacc[dblk], 0, 0, 0);
                        }
                        __builtin_amdgcn_s_setprio(0);
                    }
                }
            }
            __syncthreads();  // all reads of buf p done before next restage
        }

        // ---- 4-way parity merge (3-phase tree over dead K/V buffers).
        // mVbig slot0 = floats [0,8192) (K region), slot1 = [8192,16384) (V).
        float* mVbig = (float*)&SM[0];
        if (p >= 1) mLs[(p - 1) * 256 + g * 64 + lane] = lp;
        if (p >= 2) {
            const int sl = (p - 2) * 8192;
#pragma unroll
            for (int dblk = 0; dblk < 2; ++dblk)
#pragma unroll
                for (int r = 0; r < 16; ++r)
                    mVbig[sl + g * 2048 + (dblk * 16 + r) * 64 + lane] = oacc[dblk][r];
        }
        __syncthreads();
        if (p == 0) {
#pragma unroll
            for (int dblk = 0; dblk < 2; ++dblk)
#pragma unroll
                for (int r = 0; r < 16; ++r)
                    oacc[dblk][r] += mVbig[g * 2048 + (dblk * 16 + r) * 64 + lane];
            lp += mLs[g * 64 + lane] + mLs[256 + g * 64 + lane] + mLs[512 + g * 64 + lane];
        } else if (p == 1) {
#pragma unroll
            for (int dblk = 0; dblk < 2; ++dblk)
#pragma unroll
                for (int r = 0; r < 16; ++r)
                    oacc[dblk][r] += mVbig[8192 + g * 2048 + (dblk * 16 + r) * 64 + lane];
        }
        __syncthreads();
        if (p == 1) {  // p1 (+p3) -> slot0
#pragma unroll
            for (int dblk = 0; dblk < 2; ++dblk)
#pragma unroll
                for (int r = 0; r < 16; ++r)
                    mVbig[g * 2048 + (dblk * 16 + r) * 64 + lane] = oacc[dblk][r];
        }
        __syncthreads();
        if (p == 0) {
#pragma unroll
            for (int dblk = 0; dblk < 2; ++dblk)
#pragma unroll
                for (int r = 0; r < 16; ++r)
                    oacc[dblk][r] += mVbig[g * 2048 + (dblk * 16 + r) * 64 + lane];

            // epilogue: l = lp(self)+lp(partner l^32); O^T -> O via LDS
            // (Oe lives in slot1 region, disjoint from slot0 reads above)
            float linv = 1.0f / (lp + __shfl_xor(lp, 32));
            unsigned short* Oe = &SM[16384 + g * 2048];  // 32q x 64d, chunk-swz
#pragma unroll
            for (int dblk = 0; dblk < 2; ++dblk)
#pragma unroll
                for (int rq = 0; rq < 4; ++rq) {
                    // d = dblk*32 + rq*8 + hi*4 + (0..3), q = l31
                    unsigned plo = cvt_pk_bf16(oacc[dblk][rq * 4 + 0] * linv,
                                               oacc[dblk][rq * 4 + 1] * linv);
                    unsigned phi = cvt_pk_bf16(oacc[dblk][rq * 4 + 2] * linv,
                                               oacc[dblk][rq * 4 + 3] * linv);
                    uint2v wv;
                    wv[0] = plo; wv[1] = phi;
                    int e = l31 * 64 + (((rq + 4 * dblk) ^ r7) << 3) + hi * 4;
                    *(uint2v*)&Oe[e] = wv;
                }
            // in-wave write->read; no barrier needed (private region)
#pragma unroll
            for (int i = 0; i < 4; ++i) {
                int q2 = i * 8 + (lane >> 3);
                int e = q2 * 64 + (((lane & 7) ^ (lane >> 3)) << 3);
                short8 ov = *(const short8*)&Oe[e];
                long orow = ((long)(b * S_LEN) + row_w + q2) * D_MODEL + h * HD + (lane & 7) * 8;
                *(short8*)&O[orow] = ov;
            }
        }
        __syncthreads();  // protect merge/Oe scratch from next tsel's staging
    }
}

extern "C" void kernel_launch(void* const* d_in, const int* in_sizes, int n_in,
                              void* d_out, int out_size, void* d_ws, size_t ws_size,
                              hipStream_t stream) {
    const float* x  = (const float*)d_in[0];
    const float* wq = (const float*)d_in[n_in - 4];
    const float* wk = (const float*)d_in[n_in - 3];
    const float* wv = (const float*)d_in[n_in - 2];
    const float* wo = (const float*)d_in[n_in - 1];
    float* out = (float*)d_out;

    unsigned short* ws    = (unsigned short*)d_ws;
    unsigned short* xb    = ws;                                   // 4096 x 2048
    unsigned short* Obuf  = ws;                                   // reuses xb
    unsigned short* qkv   = xb + (long)BATCH * S_LEN * D_MODEL;   // 4096 x 3072
    unsigned short* woT   = qkv + (long)BATCH * S_LEN * QKV_N;    // 2048 x 2048
    unsigned short* wqkvT = woT + (long)D_MODEL * D_MODEL;        // 3072 x 2048
    unsigned short* Vt    = wqkvT;                                // reuses wqkvT

    const int M = BATCH * S_LEN;  // 4096

    // fused cast + weight transposes (1 launch, 18432 blocks)
    prep<<<18432, 256, 0, stream>>>(x, wq, wk, wv, wo, xb, wqkvT, woT);

    // QKV projection: 128x128 swizzled tiles (768 blocks = 3/CU)
    gemm_sw<128, false><<<dim3(M / 128, QKV_N / 128), 256, 0, stream>>>(
        xb, wqkvT, qkv, M, QKV_N, D_MODEL);

    // RoPE (all 40 heads, Q pre-scaled) + V transpose (1 launch)
    rope_vtrans<<<1024, 256, 0, stream>>>(qkv, Vt);

    flash10<<<dim3(8, NH, BATCH), 1024, 0, stream>>>(qkv, Vt, Obuf);

    // out projection: 128x128 swizzled tiles (512 blocks = 2/CU, MI=4)
    gemm_sw<128, true><<<dim3(M / 128, D_MODEL / 128), 256, 0, stream>>>(
        Obuf, woT, out, M, D_MODEL, D_MODEL);
}

// Round 9
// 300.968 us; speedup vs baseline: 2.4838x; 2.4838x over previous
//
#include <hip/hip_runtime.h>
#include <hip/hip_bf16.h>

// Attention: B=2, S=2048, D=2048, NH=32, NKV=8, HD=64, causal, RoPE, GQA.
// Inputs fp32, OUTPUT fp32. Internal bf16 MFMA, fp32 accumulate.
//
// ws layout (63 MB, bf16 elems):
//   xb/Obuf :  8,388,608 (4096x2048) — xb dead after QKV GEMM, reused as Obuf
//   qkv     : 12,582,912 (4096x3072)
//   woT     :  4,194,304 (2048x2048)
//   wqkvT/Vt:  6,291,456 — wqkvT dead after QKV GEMM, reused as Vt[b*8+kh][64][2048]
//
// Pipeline (5 launches): prep (cast + 4x weight-transpose) -> QKV GEMM ->
// rope+vtrans (all 40 heads roped, Q pre-scaled; V transposed) -> flash8 ->
// out-proj GEMM (128x128). GEMMs + flash use XCD-aware block swizzle (T1).

#define S_LEN 2048
#define BATCH 2
#define D_MODEL 2048
#define NH 32
#define NKV 8
#define HD 64
#define KV_D (NKV * HD)            // 512
#define QKV_N (D_MODEL + 2 * KV_D) // 3072

typedef __attribute__((ext_vector_type(8))) short short8;
typedef __attribute__((ext_vector_type(4))) float float4v;
typedef __attribute__((ext_vector_type(16))) float f32x16;
typedef __attribute__((ext_vector_type(2))) unsigned uint2v;

typedef __attribute__((address_space(1))) const unsigned int gu32;
typedef __attribute__((address_space(3))) unsigned int lu32;

// Q is pre-scaled by 0.125*log2(e) in rope; scores then feed v_exp_f32 (2^x) raw.
#if __has_builtin(__builtin_amdgcn_exp2f)
#define PEXP(x) __builtin_amdgcn_exp2f(x)
#else
#define PEXP(x) __expf((x) * 0.69314718f)
#endif
#define QSCALE 0.18033688f  // 0.125 * log2(e)

__device__ __forceinline__ float bf2f(unsigned short u) {
    unsigned x = ((unsigned)u) << 16;
    return __builtin_bit_cast(float, x);
}
__device__ __forceinline__ unsigned short f2bf(float f) {
    unsigned u = __builtin_bit_cast(unsigned, f);
    unsigned r = (u + 0x7fffu + ((u >> 16) & 1u)) >> 16;
    return (unsigned short)r;
}

// packed f32x2 -> bf16x2 (RNE), single instruction
__device__ __forceinline__ unsigned cvt_pk_bf16(float a, float b) {
    unsigned r;
    asm("v_cvt_pk_bf16_f32 %0, %1, %2" : "=v"(r) : "v"(a), "v"(b));
    return r;
}

// permlane32_swap(a, b) -> (x, y)
__device__ __forceinline__ void pl32swap(unsigned a, unsigned b,
                                         unsigned& x, unsigned& y) {
#if __has_builtin(__builtin_amdgcn_permlane32_swap)
    uint2v r = __builtin_amdgcn_permlane32_swap(a, b, false, false);
    x = r[0];
    y = r[1];
#else
    unsigned pa = (unsigned)__shfl_xor((int)a, 32);
    unsigned pb = (unsigned)__shfl_xor((int)b, 32);
    bool lo = (threadIdx.x & 63) < 32;
    x = lo ? a : pb;
    y = lo ? pa : b;
#endif
}

// ---- prep: fused {wq,wk,wv,wo transpose+cast} + {x fp32->bf16 cast}.
// Flat grid 18432 blocks: [0,4096) wq, [4096,5120) wk, [5120,6144) wv,
// [6144,10240) wo, [10240,18432) cast. All block-independent.
__global__ __launch_bounds__(256) void prep(const float* __restrict__ x,
                                            const float* __restrict__ wq,
                                            const float* __restrict__ wk,
                                            const float* __restrict__ wv,
                                            const float* __restrict__ wo,
                                            unsigned short* __restrict__ xb,
                                            unsigned short* __restrict__ wqkvT,
                                            unsigned short* __restrict__ woT) {
    __shared__ unsigned short t[32 * 33];
    const int bx = blockIdx.x;
    if (bx >= 10240) {  // elementwise cast, 4 elems/thread
        long i = ((long)(bx - 10240) * 256 + threadIdx.x) * 4;
        const long n = (long)BATCH * S_LEN * D_MODEL;
        if (i + 3 >= n) return;
        const float4v v = *(const float4v*)&x[i];
        unsigned short o[4];
        o[0] = f2bf(v[0]); o[1] = f2bf(v[1]); o[2] = f2bf(v[2]); o[3] = f2bf(v[3]);
        *(__attribute__((ext_vector_type(4))) short*)&xb[i] =
            *(__attribute__((ext_vector_type(4))) short*)o;
        return;
    }
    // weight transpose: out[n*K+k] = bf16(in[k*N+n]), K=2048 rows
    const float* in;
    unsigned short* out;
    int N, nb, kb;
    if (bx < 4096) {
        in = wq; out = wqkvT; N = 2048;
        nb = (bx & 63) * 32; kb = (bx >> 6) * 32;
    } else if (bx < 5120) {
        const int i2 = bx - 4096;
        in = wk; out = wqkvT + (long)D_MODEL * D_MODEL; N = 512;
        nb = (i2 & 15) * 32; kb = (i2 >> 4) * 32;
    } else if (bx < 6144) {
        const int i2 = bx - 5120;
        in = wv; out = wqkvT + (long)(D_MODEL + KV_D) * D_MODEL; N = 512;
        nb = (i2 & 15) * 32; kb = (i2 >> 4) * 32;
    } else {
        const int i2 = bx - 6144;
        in = wo; out = woT; N = 2048;
        nb = (i2 & 63) * 32; kb = (i2 >> 6) * 32;
    }
    const int c = threadIdx.x & 31, rr = threadIdx.x >> 5;
#pragma unroll
    for (int it = 0; it < 4; ++it) {
        int r = it * 8 + rr;
        t[c * 33 + r] = f2bf(in[(long)(kb + r) * N + nb + c]);
    }
    __syncthreads();
#pragma unroll
    for (int it = 0; it < 4; ++it) {
        int r = it * 8 + rr;
        out[(long)(nb + r) * D_MODEL + kb + c] = t[r * 33 + c];
    }
}

// GEMM: C(MxN) = A(MxK,bf16) * BT(NxK,bf16)^T, fp32/bf16 out.
// Tile TMx128, BK=64, global_load_lds(16) staging, XOR-swizzled LDS layout:
// row r's logical 16B chunk c stored at chunk (c ^ (r&7)) — conflict-free
// ds_read_b128 while keeping the DMA lane-contiguous.
// XCD-aware block swizzle: contiguous tile-bands per XCD (grid % 8 == 0).
template <int TM, bool F32OUT>
__global__ __launch_bounds__(256, TM == 64 ? 4 : 3)
void gemm_sw(const unsigned short* __restrict__ A,
             const unsigned short* __restrict__ BT,
             void* __restrict__ Cv, int M, int N, int K) {
    __shared__ unsigned short As[TM * 64];
    __shared__ unsigned short Bs[128 * 64];
    const int tid = threadIdx.x;
    const int wid = tid >> 6, lane = tid & 63;
    const int l15 = lane & 15, quad = lane >> 4;
    const int wm = (wid >> 1) * (TM / 2), wn = (wid & 1) * 64;

    // XCD swizzle: wgid%8 = XCD -> give each XCD a contiguous v-range.
    const int nwg = gridDim.x * gridDim.y;
    const int wgid = blockIdx.y * gridDim.x + blockIdx.x;
    const int v = (wgid & 7) * (nwg >> 3) + (wgid >> 3);
    const int row0 = (v % gridDim.x) * TM, col0 = (v / gridDim.x) * 128;
    constexpr int MI = TM / 32;  // m-frags per wave

    float4v acc[MI][4];
    float4v z;
    z[0] = z[1] = z[2] = z[3] = 0.0f;
    for (int mi = 0; mi < MI; ++mi)
        for (int ni = 0; ni < 4; ++ni) acc[mi][ni] = z;

    const int r_ld = lane >> 3;                          // 0..7 row in chunk16
    const int swz_ld = ((lane & 7) ^ (lane >> 3)) * 8;   // swizzled source col
    const int sw = l15 & 7;                              // read-side swizzle

    for (int kb = 0; kb < K; kb += 64) {
        __syncthreads();
#pragma unroll
        for (int c = 0; c < 4; ++c) {
            int chunk = c * 4 + wid;  // 16 chunks of 8 rows (B); TM/8 for A
            int r = chunk * 8 + r_ld;
            __builtin_amdgcn_global_load_lds(
                (gu32*)&BT[(long)(col0 + r) * K + kb + swz_ld],
                (lu32*)&Bs[chunk * 512], 16, 0, 0);
            if (c < MI)
                __builtin_amdgcn_global_load_lds(
                    (gu32*)&A[(long)(row0 + r) * K + kb + swz_ld],
                    (lu32*)&As[chunk * 512], 16, 0, 0);
        }
        __syncthreads();
#pragma unroll
        for (int kk = 0; kk < 64; kk += 32) {
            short8 af[MI], bf[4];
#pragma unroll
            for (int i = 0; i < MI; ++i)
                af[i] = *(const short8*)
                    &As[(wm + i * 16 + l15) * 64 + ((((kk >> 3) + quad) ^ sw) << 3)];
#pragma unroll
            for (int i = 0; i < 4; ++i)
                bf[i] = *(const short8*)
                    &Bs[(wn + i * 16 + l15) * 64 + ((((kk >> 3) + quad) ^ sw) << 3)];
#pragma unroll
            for (int mi = 0; mi < MI; ++mi)
#pragma unroll
                for (int ni = 0; ni < 4; ++ni)
                    acc[mi][ni] = __builtin_amdgcn_mfma_f32_16x16x32_bf16(
                        af[mi], bf[ni], acc[mi][ni], 0, 0, 0);
        }
    }
#pragma unroll
    for (int mi = 0; mi < MI; ++mi)
#pragma unroll
        for (int ni = 0; ni < 4; ++ni)
#pragma unroll
            for (int r = 0; r < 4; ++r) {
                int m = row0 + wm + mi * 16 + quad * 4 + r;
                int n = col0 + wn + ni * 16 + l15;
                if (F32OUT)
                    ((float*)Cv)[(long)m * N + n] = acc[mi][ni][r];
                else
                    ((unsigned short*)Cv)[(long)m * N + n] = f2bf(acc[mi][ni][r]);
            }
}

// ---- rope + vtrans, merged (independent regions of qkv).
// Blocks [0,512): RoPE all 40 heads (Q heads pre-scaled by QSCALE).
// Blocks [512,1024): V transpose qkv -> Vt[b*8+kh][64][2048].
__global__ __launch_bounds__(256) void rope_vtrans(unsigned short* __restrict__ qkv,
                                                   unsigned short* __restrict__ Vt) {
    __shared__ unsigned t[64 * 33];
    const int bx = blockIdx.x, tid = threadIdx.x;
    if (bx < 512) {
        const int i = tid & 31;
        const int row = bx * 8 + (tid >> 5);
        const int s = row & (S_LEN - 1);
        float freq = __expf(-0.28782313f * (float)i);  // 10000^(-i/32)
        float ang = (float)s * freq;
        float c = cosf(ang), sn = sinf(ang);
        unsigned* p = (unsigned*)qkv + ((long)row * QKV_N + 2 * i) / 2;
#pragma unroll
        for (int head = 0; head < 40; ++head) {
            const float qs = (head < 32) ? QSCALE : 1.0f;
            unsigned v = p[head * 32];
            float xr = bf2f((unsigned short)(v & 0xffff));
            float xi = bf2f((unsigned short)(v >> 16));
            unsigned short lo = f2bf((xr * c - xi * sn) * qs);
            unsigned short hi = f2bf((xr * sn + xi * c) * qs);
            p[head * 32] = (unsigned)lo | ((unsigned)hi << 16);
        }
        return;
    }
    const int idx = bx - 512;
    const int st = (idx & 31) * 64, kh = (idx >> 5) & 7, b = idx >> 8;
    {
        const int r2 = tid >> 3, dbase = (tid & 7) * 8;
        const unsigned short* src =
            qkv + ((long)(b * S_LEN + st + 2 * r2)) * QKV_N + D_MODEL + KV_D + kh * HD + dbase;
        short8 lo = *(const short8*)src;
        short8 hi = *(const short8*)(src + QKV_N);
#pragma unroll
        for (int j = 0; j < 8; ++j)
            t[(dbase + j) * 33 + r2] =
                (unsigned)(unsigned short)lo[j] | ((unsigned)(unsigned short)hi[j] << 16);
    }
    __syncthreads();
    {
        const int d = tid >> 2, sb = (tid & 3) * 8;
        unsigned short o[16];
#pragma unroll
        for (int jj = 0; jj < 8; ++jj) {
            unsigned v = t[d * 33 + sb + jj];
            o[2 * jj] = (unsigned short)(v & 0xffff);
            o[2 * jj + 1] = (unsigned short)(v >> 16);
        }
        unsigned short* dst =
            Vt + ((long)((b * 8 + kh) * 64 + d)) * S_LEN + st + sb * 2;
        *(short8*)dst = *(short8*)&o[0];
        *(short8*)(dst + 8) = *(short8*)&o[8];
    }
}

// Flash v8 (measured ~74 us) + XCD swizzle: parity-split k-loop for 2x TLP.
// 512-thr blocks, 8 waves: wave w = (g=w&3, p=w>>2); waves {g,g+4} process
// even/odd k-tiles concurrently (no running max -> pure sum), merged at
// epilogue via LDS. 4 LDS buffers = 64 KB -> 2 blocks/CU = 16 waves/CU.
// (qtA, 15-qtA) pairing -> uniform 17 supersteps/block.
// XCD swizzle: each XCD gets 8 consecutive heads (2 kh-groups, ~1 MB K/V)
// -> K/V panels L2-resident instead of refetched from L3 by all 8 XCDs.
__global__ __launch_bounds__(512, 4) void flash8(const unsigned short* __restrict__ qkv,
                                                 const unsigned short* __restrict__ Vt,
                                                 unsigned short* __restrict__ O) {
    __shared__ unsigned short Ks[4][64 * 64];  // [key][d], swizzled chunks
    __shared__ unsigned short Vs[4][64 * 64];  // [d][key], swizzled chunks

    const int tid = threadIdx.x, w = tid >> 6, lane = tid & 63;
    const int g = w & 3, p = w >> 2;
    const int l31 = lane & 31, hi = lane >> 5;
    const int r7 = l31 & 7;

    // XCD swizzle over the flattened 8x32x2 = 512-block grid (x fastest).
    const int wgid = (blockIdx.z * 32 + blockIdx.y) * 8 + blockIdx.x;
    const int v = (wgid & 7) * 64 + (wgid >> 3);
    const int qtA = v & 7;          // 0..7
    const int h = (v >> 3) & 31;
    const int b = v >> 8;
    const int kh = h >> 2, bkh = b * 8 + kh;

    const int sr = lane >> 3;
    const int sc = ((lane & 7) ^ sr) * 8;
    const unsigned short* Kg =
        qkv + (long)b * S_LEN * QKV_N + D_MODEL + kh * HD + sc;
    const unsigned short* Vg = Vt + ((long)bkh * 64) * S_LEN + sc;

#define STAGE8(pb)                                                                   \
    do {                                                                             \
        const int tt = (pb) + p;                                                     \
        const int bt = tt & 3;                                                       \
        const long kk0 = (long)tt * 64;                                              \
        __builtin_amdgcn_global_load_lds(                                            \
            (gu32*)&Kg[(kk0 + g * 16 + sr) * QKV_N],                                 \
            (lu32*)&Ks[bt][(g * 16) * 64], 16, 0, 0);                                \
        __builtin_amdgcn_global_load_lds(                                            \
            (gu32*)&Kg[(kk0 + g * 16 + 8 + sr) * QKV_N],                             \
            (lu32*)&Ks[bt][(g * 16 + 8) * 64], 16, 0, 0);                            \
        __builtin_amdgcn_global_load_lds(                                            \
            (gu32*)&Vg[(long)(g * 16 + sr) * S_LEN + kk0],                           \
            (lu32*)&Vs[bt][(g * 16) * 64], 16, 0, 0);                                \
        __builtin_amdgcn_global_load_lds(                                            \
            (gu32*)&Vg[(long)(g * 16 + 8 + sr) * S_LEN + kk0],                       \
            (lu32*)&Vs[bt][(g * 16 + 8) * 64], 16, 0, 0);                            \
    } while (0)

    for (int tsel = 0; tsel < 2; ++tsel) {
        const int qt = tsel ? (15 - qtA) : qtA;
        const int row_w = qt * 128 + g * 32;
        const int nkt = 2 * qt + 2;   // even
        const int nss = nkt >> 1;     // supersteps

        // Q B-frags: lane holds col q = l31, d-rows ks*16 + hi*8 + 0..7
        short8 aq[4];
        {
            const long qbase = ((long)(b * S_LEN) + row_w + l31) * QKV_N + h * HD + hi * 8;
#pragma unroll
            for (int ks = 0; ks < 4; ++ks) aq[ks] = *(const short8*)&qkv[qbase + ks * 16];
        }

        f32x16 oacc[2] = {};
        float lp = 0.0f;

        STAGE8(0);  // tiles 0 (p=0), 1 (p=1)
        __syncthreads();

        for (int ss = 0; ss < nss; ++ss) {
            const int t = 2 * ss + p;
            const int k0 = t * 64;
            const int bt = t & 3;
            if (2 * ss + 2 < nkt) STAGE8(2 * ss + 2);

            if (row_w + 31 >= k0) {  // wave-uniform-per-wave: skip masked tiles
                const bool mb = (k0 + 63 > row_w);
#pragma unroll
                for (int kb2 = 0; kb2 < 2; ++kb2) {
                    short8 kf[4];
#pragma unroll
                    for (int ks = 0; ks < 4; ++ks)
                        kf[ks] = *(const short8*)
                            &Ks[bt][(kb2 * 32 + l31) * 64 + (((ks * 2 + hi) ^ r7) << 3)];
                    f32x16 s = {};
                    __builtin_amdgcn_s_setprio(1);
#pragma unroll
                    for (int ks = 0; ks < 4; ++ks)
                        s = __builtin_amdgcn_mfma_f32_32x32x16_bf16(kf[ks], aq[ks], s, 0, 0, 0);
                    __builtin_amdgcn_s_setprio(0);

                    // s row = key = kb2*32 + (r&3)+8*(r>>2)+4*hi, col q = l31
                    const int qrel = row_w + l31 - k0 - kb2 * 32 - 4 * hi;
#pragma unroll
                    for (int r = 0; r < 16; ++r) {
                        float vv = s[r];
                        if (mb && ((r & 3) + 8 * (r >> 2) > qrel)) vv = -1e4f;
                        float pv = PEXP(vv);
                        lp += pv;
                        s[r] = pv;
                    }

                    // P^T B-frags in-register (cvt_pk + permlane32_swap), then PV
#pragma unroll
                    for (int ksl = 0; ksl < 2; ++ksl) {
                        const int gx = ksl * 8;
                        unsigned ca = cvt_pk_bf16(s[gx + 0], s[gx + 1]);
                        unsigned cb = cvt_pk_bf16(s[gx + 2], s[gx + 3]);
                        unsigned cc = cvt_pk_bf16(s[gx + 4], s[gx + 5]);
                        unsigned cd = cvt_pk_bf16(s[gx + 6], s[gx + 7]);
                        unsigned dw0, dw1, dw2, dw3;
                        pl32swap(ca, cc, dw0, dw2);
                        pl32swap(cb, cd, dw1, dw3);
                        union { unsigned u[4]; short8 v8; } pf;
                        pf.u[0] = dw0; pf.u[1] = dw1; pf.u[2] = dw2; pf.u[3] = dw3;
                        const int lc = kb2 * 4 + ksl * 2 + hi;
                        __builtin_amdgcn_s_setprio(1);
#pragma unroll
                        for (int dblk = 0; dblk < 2; ++dblk) {
                            short8 vf = *(const short8*)
                                &Vs[bt][(dblk * 32 + l31) * 64 + ((lc ^ r7) << 3)];
                            oacc[dblk] = __builtin_amdgcn_mfma_f32_32x32x16_bf16(
                                vf, pf.v8, oacc[dblk], 0, 0, 0);
                        }
                        __builtin_amdgcn_s_setprio(0);
                    }
                }
            }
            __syncthreads();  // bufs (2ss,2ss+1) consumed; safe to restage
        }

        // ---- merge parity partials via LDS ([j][lane] layout, conflict-free)
        float* mV = (float*)&Vs[0][0];        // 4g x 32j x 64lane f32 = 32 KB
        float* mL = (float*)&Ks[2][0];        // 4g x 64lane f32 = 1 KB
        if (p == 1) {
#pragma unroll
            for (int dblk = 0; dblk < 2; ++dblk)
#pragma unroll
                for (int r = 0; r < 16; ++r)
                    mV[(g * 32 + dblk * 16 + r) * 64 + lane] = oacc[dblk][r];
            mL[g * 64 + lane] = lp;
        }
        __syncthreads();
        if (p == 0) {
#pragma unroll
            for (int dblk = 0; dblk < 2; ++dblk)
#pragma unroll
                for (int r = 0; r < 16; ++r)
                    oacc[dblk][r] += mV[(g * 32 + dblk * 16 + r) * 64 + lane];
            lp += mL[g * 64 + lane];

            // epilogue: l = lp(self) + lp(partner l^32); O^T -> O via LDS
            float linv = 1.0f / (lp + __shfl_xor(lp, 32));
            unsigned short* Oe = &Ks[0][0] + g * 2048;  // 32q x 64d, chunk-swz
#pragma unroll
            for (int dblk = 0; dblk < 2; ++dblk)
#pragma unroll
                for (int rq = 0; rq < 4; ++rq) {
                    // d = dblk*32 + rq*8 + hi*4 + (0..3), q = l31
                    unsigned plo = cvt_pk_bf16(oacc[dblk][rq * 4 + 0] * linv,
                                               oacc[dblk][rq * 4 + 1] * linv);
                    unsigned phi = cvt_pk_bf16(oacc[dblk][rq * 4 + 2] * linv,
                                               oacc[dblk][rq * 4 + 3] * linv);
                    uint2v wv;
                    wv[0] = plo; wv[1] = phi;
                    int e = l31 * 64 + (((rq + 4 * dblk) ^ r7) << 3) + hi * 4;
                    *(uint2v*)&Oe[e] = wv;
                }
            // in-wave write->read; no barrier needed (private region)
#pragma unroll
            for (int i = 0; i < 4; ++i) {
                int q2 = i * 8 + (lane >> 3);
                int e = q2 * 64 + (((lane & 7) ^ (lane >> 3)) << 3);
                short8 ov = *(const short8*)&Oe[e];
                long orow = ((long)(b * S_LEN) + row_w + q2) * D_MODEL + h * HD + (lane & 7) * 8;
                *(short8*)&O[orow] = ov;
            }
        }
        __syncthreads();  // protect merge/Oe scratch from next tsel's staging
    }
#undef STAGE8
}

extern "C" void kernel_launch(void* const* d_in, const int* in_sizes, int n_in,
                              void* d_out, int out_size, void* d_ws, size_t ws_size,
                              hipStream_t stream) {
    const float* x  = (const float*)d_in[0];
    const float* wq = (const float*)d_in[n_in - 4];
    const float* wk = (const float*)d_in[n_in - 3];
    const float* wv = (const float*)d_in[n_in - 2];
    const float* wo = (const float*)d_in[n_in - 1];
    float* out = (float*)d_out;

    unsigned short* ws    = (unsigned short*)d_ws;
    unsigned short* xb    = ws;                                   // 4096 x 2048
    unsigned short* Obuf  = ws;                                   // reuses xb
    unsigned short* qkv   = xb + (long)BATCH * S_LEN * D_MODEL;   // 4096 x 3072
    unsigned short* woT   = qkv + (long)BATCH * S_LEN * QKV_N;    // 2048 x 2048
    unsigned short* wqkvT = woT + (long)D_MODEL * D_MODEL;        // 3072 x 2048
    unsigned short* Vt    = wqkvT;                                // reuses wqkvT

    const int M = BATCH * S_LEN;  // 4096

    // fused cast + weight transposes (1 launch, 18432 blocks)
    prep<<<18432, 256, 0, stream>>>(x, wq, wk, wv, wo, xb, wqkvT, woT);

    // QKV projection: 128x128 swizzled tiles (768 blocks = 3/CU)
    gemm_sw<128, false><<<dim3(M / 128, QKV_N / 128), 256, 0, stream>>>(
        xb, wqkvT, qkv, M, QKV_N, D_MODEL);

    // RoPE (all 40 heads, Q pre-scaled) + V transpose (1 launch)
    rope_vtrans<<<1024, 256, 0, stream>>>(qkv, Vt);

    flash8<<<dim3(8, NH, BATCH), 512, 0, stream>>>(qkv, Vt, Obuf);

    // out projection: 128x128 swizzled tiles (512 blocks = 2/CU, MI=4)
    gemm_sw<128, true><<<dim3(M / 128, D_MODEL / 128), 256, 0, stream>>>(
        Obuf, woT, out, M, D_MODEL, D_MODEL);
}

// Round 10
// 287.228 us; speedup vs baseline: 2.6027x; 1.0478x over previous
//
#include <hip/hip_runtime.h>
#include <hip/hip_bf16.h>

// Attention: B=2, S=2048, D=2048, NH=32, NKV=8, HD=64, causal, RoPE, GQA.
// Inputs fp32, OUTPUT fp32. Internal bf16 MFMA, fp32 accumulate.
//
// ws layout (63 MB, bf16 elems):
//   xb/Obuf :  8,388,608 (4096x2048) — xb dead after QKV GEMM, reused as Obuf
//   qkv     : 12,582,912 (4096x3072)
//   woT     :  4,194,304 (2048x2048)
//   wqkvT/Vt:  6,291,456 — wqkvT dead after QKV GEMM, reused as Vt[b*8+kh][64][2048]
//
// Pipeline (5 launches): prep -> QKV GEMM (gemm9: 256^2, counted-vmcnt
// 4-phase pipeline) -> rope+vtrans -> flash8 (XCD-swizzled) -> out-proj
// gemm_sw<128> (default dispatch order — XCD swizzle hurt here, reverted).

#define S_LEN 2048
#define BATCH 2
#define D_MODEL 2048
#define NH 32
#define NKV 8
#define HD 64
#define KV_D (NKV * HD)            // 512
#define QKV_N (D_MODEL + 2 * KV_D) // 3072

typedef __attribute__((ext_vector_type(8))) short short8;
typedef __attribute__((ext_vector_type(4))) float float4v;
typedef __attribute__((ext_vector_type(16))) float f32x16;
typedef __attribute__((ext_vector_type(2))) unsigned uint2v;

typedef __attribute__((address_space(1))) const unsigned int gu32;
typedef __attribute__((address_space(3))) unsigned int lu32;

// Q is pre-scaled by 0.125*log2(e) in rope; scores then feed v_exp_f32 (2^x) raw.
#if __has_builtin(__builtin_amdgcn_exp2f)
#define PEXP(x) __builtin_amdgcn_exp2f(x)
#else
#define PEXP(x) __expf((x) * 0.69314718f)
#endif
#define QSCALE 0.18033688f  // 0.125 * log2(e)

__device__ __forceinline__ float bf2f(unsigned short u) {
    unsigned x = ((unsigned)u) << 16;
    return __builtin_bit_cast(float, x);
}
__device__ __forceinline__ unsigned short f2bf(float f) {
    unsigned u = __builtin_bit_cast(unsigned, f);
    unsigned r = (u + 0x7fffu + ((u >> 16) & 1u)) >> 16;
    return (unsigned short)r;
}

// packed f32x2 -> bf16x2 (RNE), single instruction
__device__ __forceinline__ unsigned cvt_pk_bf16(float a, float b) {
    unsigned r;
    asm("v_cvt_pk_bf16_f32 %0, %1, %2" : "=v"(r) : "v"(a), "v"(b));
    return r;
}

// permlane32_swap(a, b) -> (x, y)
__device__ __forceinline__ void pl32swap(unsigned a, unsigned b,
                                         unsigned& x, unsigned& y) {
#if __has_builtin(__builtin_amdgcn_permlane32_swap)
    uint2v r = __builtin_amdgcn_permlane32_swap(a, b, false, false);
    x = r[0];
    y = r[1];
#else
    unsigned pa = (unsigned)__shfl_xor((int)a, 32);
    unsigned pb = (unsigned)__shfl_xor((int)b, 32);
    bool lo = (threadIdx.x & 63) < 32;
    x = lo ? a : pb;
    y = lo ? pa : b;
#endif
}

// ---- prep: fused {wq,wk,wv,wo transpose+cast} + {x fp32->bf16 cast}.
__global__ __launch_bounds__(256) void prep(const float* __restrict__ x,
                                            const float* __restrict__ wq,
                                            const float* __restrict__ wk,
                                            const float* __restrict__ wv,
                                            const float* __restrict__ wo,
                                            unsigned short* __restrict__ xb,
                                            unsigned short* __restrict__ wqkvT,
                                            unsigned short* __restrict__ woT) {
    __shared__ unsigned short t[32 * 33];
    const int bx = blockIdx.x;
    if (bx >= 10240) {  // elementwise cast, 4 elems/thread
        long i = ((long)(bx - 10240) * 256 + threadIdx.x) * 4;
        const long n = (long)BATCH * S_LEN * D_MODEL;
        if (i + 3 >= n) return;
        const float4v v = *(const float4v*)&x[i];
        unsigned short o[4];
        o[0] = f2bf(v[0]); o[1] = f2bf(v[1]); o[2] = f2bf(v[2]); o[3] = f2bf(v[3]);
        *(__attribute__((ext_vector_type(4))) short*)&xb[i] =
            *(__attribute__((ext_vector_type(4))) short*)o;
        return;
    }
    const float* in;
    unsigned short* out;
    int N, nb, kb;
    if (bx < 4096) {
        in = wq; out = wqkvT; N = 2048;
        nb = (bx & 63) * 32; kb = (bx >> 6) * 32;
    } else if (bx < 5120) {
        const int i2 = bx - 4096;
        in = wk; out = wqkvT + (long)D_MODEL * D_MODEL; N = 512;
        nb = (i2 & 15) * 32; kb = (i2 >> 4) * 32;
    } else if (bx < 6144) {
        const int i2 = bx - 5120;
        in = wv; out = wqkvT + (long)(D_MODEL + KV_D) * D_MODEL; N = 512;
        nb = (i2 & 15) * 32; kb = (i2 >> 4) * 32;
    } else {
        const int i2 = bx - 6144;
        in = wo; out = woT; N = 2048;
        nb = (i2 & 63) * 32; kb = (i2 >> 6) * 32;
    }
    const int c = threadIdx.x & 31, rr = threadIdx.x >> 5;
#pragma unroll
    for (int it = 0; it < 4; ++it) {
        int r = it * 8 + rr;
        t[c * 33 + r] = f2bf(in[(long)(kb + r) * N + nb + c]);
    }
    __syncthreads();
#pragma unroll
    for (int it = 0; it < 4; ++it) {
        int r = it * 8 + rr;
        out[(long)(nb + r) * D_MODEL + kb + c] = t[r * 33 + c];
    }
}

// GEMM: C(MxN) = A(MxK,bf16) * BT(NxK,bf16)^T, fp32/bf16 out.
// Tile TMx128, BK=64, global_load_lds(16) staging, XOR-swizzled LDS layout.
// Default dispatch order (XCD swizzle REGRESSED here: default already keeps
// each XCD's A row-panels L2-resident; round-9 A/B = +13 us).
template <int TM, bool F32OUT>
__global__ __launch_bounds__(256, TM == 64 ? 4 : 3)
void gemm_sw(const unsigned short* __restrict__ A,
             const unsigned short* __restrict__ BT,
             void* __restrict__ Cv, int M, int N, int K) {
    __shared__ unsigned short As[TM * 64];
    __shared__ unsigned short Bs[128 * 64];
    const int tid = threadIdx.x;
    const int wid = tid >> 6, lane = tid & 63;
    const int l15 = lane & 15, quad = lane >> 4;
    const int wm = (wid >> 1) * (TM / 2), wn = (wid & 1) * 64;
    const int row0 = blockIdx.x * TM, col0 = blockIdx.y * 128;
    constexpr int MI = TM / 32;  // m-frags per wave

    float4v acc[MI][4];
    float4v z;
    z[0] = z[1] = z[2] = z[3] = 0.0f;
    for (int mi = 0; mi < MI; ++mi)
        for (int ni = 0; ni < 4; ++ni) acc[mi][ni] = z;

    const int r_ld = lane >> 3;                          // 0..7 row in chunk16
    const int swz_ld = ((lane & 7) ^ (lane >> 3)) * 8;   // swizzled source col
    const int sw = l15 & 7;                              // read-side swizzle

    for (int kb = 0; kb < K; kb += 64) {
        __syncthreads();
#pragma unroll
        for (int c = 0; c < 4; ++c) {
            int chunk = c * 4 + wid;  // 16 chunks of 8 rows (B); TM/8 for A
            int r = chunk * 8 + r_ld;
            __builtin_amdgcn_global_load_lds(
                (gu32*)&BT[(long)(col0 + r) * K + kb + swz_ld],
                (lu32*)&Bs[chunk * 512], 16, 0, 0);
            if (c < MI)
                __builtin_amdgcn_global_load_lds(
                    (gu32*)&A[(long)(row0 + r) * K + kb + swz_ld],
                    (lu32*)&As[chunk * 512], 16, 0, 0);
        }
        __syncthreads();
#pragma unroll
        for (int kk = 0; kk < 64; kk += 32) {
            short8 af[MI], bf[4];
#pragma unroll
            for (int i = 0; i < MI; ++i)
                af[i] = *(const short8*)
                    &As[(wm + i * 16 + l15) * 64 + ((((kk >> 3) + quad) ^ sw) << 3)];
#pragma unroll
            for (int i = 0; i < 4; ++i)
                bf[i] = *(const short8*)
                    &Bs[(wn + i * 16 + l15) * 64 + ((((kk >> 3) + quad) ^ sw) << 3)];
#pragma unroll
            for (int mi = 0; mi < MI; ++mi)
#pragma unroll
                for (int ni = 0; ni < 4; ++ni)
                    acc[mi][ni] = __builtin_amdgcn_mfma_f32_16x16x32_bf16(
                        af[mi], bf[ni], acc[mi][ni], 0, 0, 0);
        }
    }
#pragma unroll
    for (int mi = 0; mi < MI; ++mi)
#pragma unroll
        for (int ni = 0; ni < 4; ++ni)
#pragma unroll
            for (int r = 0; r < 4; ++r) {
                int m = row0 + wm + mi * 16 + quad * 4 + r;
                int n = col0 + wn + ni * 16 + l15;
                if (F32OUT)
                    ((float*)Cv)[(long)m * N + n] = acc[mi][ni][r];
                else
                    ((unsigned short*)Cv)[(long)m * N + n] = f2bf(acc[mi][ni][r]);
            }
}

// ---------------- gemm9: QKV projection, counted-vmcnt pipeline -----------
// C(4096x3072,bf16) = A(4096x2048) * BT(3072x2048)^T. 256^2 tile, BK=64,
// 512 thr = 8 waves (2M x 4N). Fragment/staging code = round-4 gemm8
// (refcheck-passed) verbatim; ONLY the wait/issue schedule changed:
// staging for tile t+1 issued 2-loads-per-phase in CONSUMPTION order
// (A01 | B01 | B23 | A23), and every phase waits s_waitcnt vmcnt(4) —
// never vmcnt(0) in the main loop (T4: counted-vs-drain0 = +38-73%, m218).
// Each load has ~3 MFMA phases between issue and required-complete.
// Last tile decays 4 -> 2 -> 0. Buffers: strict dbuf, write-opposite only.
#define K8 2048
#define N8 3072
#define NK8 (K8 / 64)

__device__ __forceinline__ void rd_a8(short8 (&a)[4][2], const unsigned short* L,
                                      int mh, int wr, int l15, int quad, int sw) {
#pragma unroll
    for (int i = 0; i < 4; ++i) {
        const int ra = mh * 128 + i * 32 + wr * 16 + l15;
#pragma unroll
        for (int kk = 0; kk < 2; ++kk)
            a[i][kk] = *(const short8*)&L[ra * 64 + (((kk * 4 + quad) ^ sw) << 3)];
    }
}
__device__ __forceinline__ void rd_b8(short8 (&b)[2][2], const unsigned short* L,
                                      int nh, int wc, int l15, int quad, int sw) {
#pragma unroll
    for (int j = 0; j < 2; ++j) {
        const int rb = nh * 128 + j * 64 + wc * 16 + l15;
#pragma unroll
        for (int kk = 0; kk < 2; ++kk)
            b[j][kk] = *(const short8*)&L[rb * 64 + (((kk * 4 + quad) ^ sw) << 3)];
    }
}
__device__ __forceinline__ void mm8(float4v (&acc)[4][2], const short8 (&a)[4][2],
                                    const short8 (&b)[2][2]) {
#pragma unroll
    for (int kk = 0; kk < 2; ++kk)
#pragma unroll
        for (int i = 0; i < 4; ++i)
#pragma unroll
            for (int j = 0; j < 2; ++j)
                acc[i][j] = __builtin_amdgcn_mfma_f32_16x16x32_bf16(
                    a[i][kk], b[j][kk], acc[i][j], 0, 0, 0);
}

__global__ __launch_bounds__(512, 2)
void gemm9(const unsigned short* __restrict__ A,
           const unsigned short* __restrict__ BT,
           unsigned short* __restrict__ C) {
    __shared__ unsigned short As[2][256 * 64];
    __shared__ unsigned short Bs[2][256 * 64];
    const int tid = threadIdx.x, wid = tid >> 6, lane = tid & 63;
    const int l15 = lane & 15, quad = lane >> 4, sw = l15 & 7;
    const int wr = wid >> 2, wc = wid & 3;  // 2M x 4N wave grid
    const int row0 = blockIdx.x * 256, col0 = blockIdx.y * 256;

    const int sr = lane >> 3;
    const int sc = ((lane & 7) ^ sr) * 8;
    const unsigned short* Ag = A + (long)(row0 + wid * 8 + sr) * K8 + sc;
    const unsigned short* Bg = BT + (long)(col0 + wid * 8 + sr) * K8 + sc;

#define STA9(buf, kb, u)                                                \
    __builtin_amdgcn_global_load_lds(                                   \
        (gu32*)(Ag + (long)(u) * (64L * K8) + (kb)),                    \
        (lu32*)&As[buf][((u) * 64 + wid * 8) * 64], 16, 0, 0)
#define STB9(buf, kb, u)                                                \
    __builtin_amdgcn_global_load_lds(                                   \
        (gu32*)(Bg + (long)(u) * (64L * K8) + (kb)),                    \
        (lu32*)&Bs[buf][((u) * 64 + wid * 8) * 64], 16, 0, 0)
// counted wait (own wave) + block barrier; "memory" clobbers pin ds ops.
#define WAITB(n)                                                        \
    do {                                                                \
        asm volatile("s_waitcnt vmcnt(" #n ")" ::: "memory");           \
        __builtin_amdgcn_s_barrier();                                   \
        asm volatile("" ::: "memory");                                  \
    } while (0)

    float4v acc[2][2][4][2];  // [mh][nh][i][j]
#pragma unroll
    for (int mh = 0; mh < 2; ++mh)
#pragma unroll
        for (int nh = 0; nh < 2; ++nh)
#pragma unroll
            for (int i = 0; i < 4; ++i)
#pragma unroll
                for (int j = 0; j < 2; ++j) {
                    acc[mh][nh][i][j][0] = 0.0f; acc[mh][nh][i][j][1] = 0.0f;
                    acc[mh][nh][i][j][2] = 0.0f; acc[mh][nh][i][j][3] = 0.0f;
                }

    // prologue: tile 0 staged in consumption order (A01 B01 B23 A23)
    STA9(0, 0, 0); STA9(0, 0, 1); STB9(0, 0, 0); STB9(0, 0, 1);
    STB9(0, 0, 2); STB9(0, 0, 3); STA9(0, 0, 2); STA9(0, 0, 3);

    for (int t = 0; t < NK8; ++t) {
        const int ct = t & 1, nx = ct ^ 1;
        const int kb = (t + 1) * 64;
        const bool more = (t + 1 < NK8);
        const unsigned short* Al = As[ct];
        const unsigned short* Bl = Bs[ct];
        short8 a0[4][2], a1[4][2], b0v[2][2], b1v[2][2];

        // ph0: consumes A01+B01 (queue head 4 of 8) -> vmcnt(4)
        WAITB(4);
        rd_a8(a0, Al, 0, wr, l15, quad, sw);
        rd_b8(b0v, Bl, 0, wc, l15, quad, sw);
        if (more) { STA9(nx, kb, 0); STA9(nx, kb, 1); }
        __builtin_amdgcn_s_setprio(1);
        mm8(acc[0][0], a0, b0v);
        __builtin_amdgcn_s_setprio(0);

        // ph1: consumes B23
        if (more) { WAITB(4); } else { WAITB(2); }
        rd_b8(b1v, Bl, 1, wc, l15, quad, sw);
        if (more) { STB9(nx, kb, 0); STB9(nx, kb, 1); }
        __builtin_amdgcn_s_setprio(1);
        mm8(acc[0][1], a0, b1v);
        __builtin_amdgcn_s_setprio(0);

        // ph2: consumes A23
        if (more) { WAITB(4); } else { WAITB(0); }
        rd_a8(a1, Al, 1, wr, l15, quad, sw);
        if (more) { STB9(nx, kb, 2); STB9(nx, kb, 3); }
        __builtin_amdgcn_s_setprio(1);
        mm8(acc[1][0], a1, b0v);
        __builtin_amdgcn_s_setprio(0);

        // ph3: reg-only (no wait, no barrier)
        if (more) { STA9(nx, kb, 2); STA9(nx, kb, 3); }
        __builtin_amdgcn_s_setprio(1);
        mm8(acc[1][1], a1, b1v);
        __builtin_amdgcn_s_setprio(0);
    }

#pragma unroll
    for (int mh = 0; mh < 2; ++mh)
#pragma unroll
        for (int nh = 0; nh < 2; ++nh)
#pragma unroll
            for (int i = 0; i < 4; ++i)
#pragma unroll
                for (int j = 0; j < 2; ++j)
#pragma unroll
                    for (int r = 0; r < 4; ++r) {
                        int m = row0 + mh * 128 + i * 32 + wr * 16 + quad * 4 + r;
                        int n = col0 + nh * 128 + j * 64 + wc * 16 + l15;
                        C[(long)m * N8 + n] = f2bf(acc[mh][nh][i][j][r]);
                    }
#undef STA9
#undef STB9
#undef WAITB
}

// ---- rope + vtrans, merged (independent regions of qkv).
__global__ __launch_bounds__(256) void rope_vtrans(unsigned short* __restrict__ qkv,
                                                   unsigned short* __restrict__ Vt) {
    __shared__ unsigned t[64 * 33];
    const int bx = blockIdx.x, tid = threadIdx.x;
    if (bx < 512) {
        const int i = tid & 31;
        const int row = bx * 8 + (tid >> 5);
        const int s = row & (S_LEN - 1);
        float freq = __expf(-0.28782313f * (float)i);  // 10000^(-i/32)
        float ang = (float)s * freq;
        float c = cosf(ang), sn = sinf(ang);
        unsigned* p = (unsigned*)qkv + ((long)row * QKV_N + 2 * i) / 2;
#pragma unroll
        for (int head = 0; head < 40; ++head) {
            const float qs = (head < 32) ? QSCALE : 1.0f;
            unsigned v = p[head * 32];
            float xr = bf2f((unsigned short)(v & 0xffff));
            float xi = bf2f((unsigned short)(v >> 16));
            unsigned short lo = f2bf((xr * c - xi * sn) * qs);
            unsigned short hi = f2bf((xr * sn + xi * c) * qs);
            p[head * 32] = (unsigned)lo | ((unsigned)hi << 16);
        }
        return;
    }
    const int idx = bx - 512;
    const int st = (idx & 31) * 64, kh = (idx >> 5) & 7, b = idx >> 8;
    {
        const int r2 = tid >> 3, dbase = (tid & 7) * 8;
        const unsigned short* src =
            qkv + ((long)(b * S_LEN + st + 2 * r2)) * QKV_N + D_MODEL + KV_D + kh * HD + dbase;
        short8 lo = *(const short8*)src;
        short8 hi = *(const short8*)(src + QKV_N);
#pragma unroll
        for (int j = 0; j < 8; ++j)
            t[(dbase + j) * 33 + r2] =
                (unsigned)(unsigned short)lo[j] | ((unsigned)(unsigned short)hi[j] << 16);
    }
    __syncthreads();
    {
        const int d = tid >> 2, sb = (tid & 3) * 8;
        unsigned short o[16];
#pragma unroll
        for (int jj = 0; jj < 8; ++jj) {
            unsigned v = t[d * 33 + sb + jj];
            o[2 * jj] = (unsigned short)(v & 0xffff);
            o[2 * jj + 1] = (unsigned short)(v >> 16);
        }
        unsigned short* dst =
            Vt + ((long)((b * 8 + kh) * 64 + d)) * S_LEN + st + sb * 2;
        *(short8*)dst = *(short8*)&o[0];
        *(short8*)(dst + 8) = *(short8*)&o[8];
    }
}

// Flash v8 + XCD swizzle (round-9 verbatim: FETCH 56->26 MB, dur -1.3 us).
__global__ __launch_bounds__(512, 4) void flash8(const unsigned short* __restrict__ qkv,
                                                 const unsigned short* __restrict__ Vt,
                                                 unsigned short* __restrict__ O) {
    __shared__ unsigned short Ks[4][64 * 64];  // [key][d], swizzled chunks
    __shared__ unsigned short Vs[4][64 * 64];  // [d][key], swizzled chunks

    const int tid = threadIdx.x, w = tid >> 6, lane = tid & 63;
    const int g = w & 3, p = w >> 2;
    const int l31 = lane & 31, hi = lane >> 5;
    const int r7 = l31 & 7;

    // XCD swizzle over the flattened 8x32x2 = 512-block grid (x fastest).
    const int wgid = (blockIdx.z * 32 + blockIdx.y) * 8 + blockIdx.x;
    const int v = (wgid & 7) * 64 + (wgid >> 3);
    const int qtA = v & 7;          // 0..7
    const int h = (v >> 3) & 31;
    const int b = v >> 8;
    const int kh = h >> 2, bkh = b * 8 + kh;

    const int sr = lane >> 3;
    const int sc = ((lane & 7) ^ sr) * 8;
    const unsigned short* Kg =
        qkv + (long)b * S_LEN * QKV_N + D_MODEL + kh * HD + sc;
    const unsigned short* Vg = Vt + ((long)bkh * 64) * S_LEN + sc;

#define STAGE8(pb)                                                                   \
    do {                                                                             \
        const int tt = (pb) + p;                                                     \
        const int bt = tt & 3;                                                       \
        const long kk0 = (long)tt * 64;                                              \
        __builtin_amdgcn_global_load_lds(                                            \
            (gu32*)&Kg[(kk0 + g * 16 + sr) * QKV_N],                                 \
            (lu32*)&Ks[bt][(g * 16) * 64], 16, 0, 0);                                \
        __builtin_amdgcn_global_load_lds(                                            \
            (gu32*)&Kg[(kk0 + g * 16 + 8 + sr) * QKV_N],                             \
            (lu32*)&Ks[bt][(g * 16 + 8) * 64], 16, 0, 0);                            \
        __builtin_amdgcn_global_load_lds(                                            \
            (gu32*)&Vg[(long)(g * 16 + sr) * S_LEN + kk0],                           \
            (lu32*)&Vs[bt][(g * 16) * 64], 16, 0, 0);                                \
        __builtin_amdgcn_global_load_lds(                                            \
            (gu32*)&Vg[(long)(g * 16 + 8 + sr) * S_LEN + kk0],                       \
            (lu32*)&Vs[bt][(g * 16 + 8) * 64], 16, 0, 0);                            \
    } while (0)

    for (int tsel = 0; tsel < 2; ++tsel) {
        const int qt = tsel ? (15 - qtA) : qtA;
        const int row_w = qt * 128 + g * 32;
        const int nkt = 2 * qt + 2;   // even
        const int nss = nkt >> 1;     // supersteps

        // Q B-frags: lane holds col q = l31, d-rows ks*16 + hi*8 + 0..7
        short8 aq[4];
        {
            const long qbase = ((long)(b * S_LEN) + row_w + l31) * QKV_N + h * HD + hi * 8;
#pragma unroll
            for (int ks = 0; ks < 4; ++ks) aq[ks] = *(const short8*)&qkv[qbase + ks * 16];
        }

        f32x16 oacc[2] = {};
        float lp = 0.0f;

        STAGE8(0);  // tiles 0 (p=0), 1 (p=1)
        __syncthreads();

        for (int ss = 0; ss < nss; ++ss) {
            const int t = 2 * ss + p;
            const int k0 = t * 64;
            const int bt = t & 3;
            if (2 * ss + 2 < nkt) STAGE8(2 * ss + 2);

            if (row_w + 31 >= k0) {  // wave-uniform-per-wave: skip masked tiles
                const bool mb = (k0 + 63 > row_w);
#pragma unroll
                for (int kb2 = 0; kb2 < 2; ++kb2) {
                    short8 kf[4];
#pragma unroll
                    for (int ks = 0; ks < 4; ++ks)
                        kf[ks] = *(const short8*)
                            &Ks[bt][(kb2 * 32 + l31) * 64 + (((ks * 2 + hi) ^ r7) << 3)];
                    f32x16 s = {};
                    __builtin_amdgcn_s_setprio(1);
#pragma unroll
                    for (int ks = 0; ks < 4; ++ks)
                        s = __builtin_amdgcn_mfma_f32_32x32x16_bf16(kf[ks], aq[ks], s, 0, 0, 0);
                    __builtin_amdgcn_s_setprio(0);

                    // s row = key = kb2*32 + (r&3)+8*(r>>2)+4*hi, col q = l31
                    const int qrel = row_w + l31 - k0 - kb2 * 32 - 4 * hi;
#pragma unroll
                    for (int r = 0; r < 16; ++r) {
                        float vv = s[r];
                        if (mb && ((r & 3) + 8 * (r >> 2) > qrel)) vv = -1e4f;
                        float pv = PEXP(vv);
                        lp += pv;
                        s[r] = pv;
                    }

                    // P^T B-frags in-register (cvt_pk + permlane32_swap), then PV
#pragma unroll
                    for (int ksl = 0; ksl < 2; ++ksl) {
                        const int gx = ksl * 8;
                        unsigned ca = cvt_pk_bf16(s[gx + 0], s[gx + 1]);
                        unsigned cb = cvt_pk_bf16(s[gx + 2], s[gx + 3]);
                        unsigned cc = cvt_pk_bf16(s[gx + 4], s[gx + 5]);
                        unsigned cd = cvt_pk_bf16(s[gx + 6], s[gx + 7]);
                        unsigned dw0, dw1, dw2, dw3;
                        pl32swap(ca, cc, dw0, dw2);
                        pl32swap(cb, cd, dw1, dw3);
                        union { unsigned u[4]; short8 v8; } pf;
                        pf.u[0] = dw0; pf.u[1] = dw1; pf.u[2] = dw2; pf.u[3] = dw3;
                        const int lc = kb2 * 4 + ksl * 2 + hi;
                        __builtin_amdgcn_s_setprio(1);
#pragma unroll
                        for (int dblk = 0; dblk < 2; ++dblk) {
                            short8 vf = *(const short8*)
                                &Vs[bt][(dblk * 32 + l31) * 64 + ((lc ^ r7) << 3)];
                            oacc[dblk] = __builtin_amdgcn_mfma_f32_32x32x16_bf16(
                                vf, pf.v8, oacc[dblk], 0, 0, 0);
                        }
                        __builtin_amdgcn_s_setprio(0);
                    }
                }
            }
            __syncthreads();  // bufs (2ss,2ss+1) consumed; safe to restage
        }

        // ---- merge parity partials via LDS ([j][lane] layout, conflict-free)
        float* mV = (float*)&Vs[0][0];        // 4g x 32j x 64lane f32 = 32 KB
        float* mL = (float*)&Ks[2][0];        // 4g x 64lane f32 = 1 KB
        if (p == 1) {
#pragma unroll
            for (int dblk = 0; dblk < 2; ++dblk)
#pragma unroll
                for (int r = 0; r < 16; ++r)
                    mV[(g * 32 + dblk * 16 + r) * 64 + lane] = oacc[dblk][r];
            mL[g * 64 + lane] = lp;
        }
        __syncthreads();
        if (p == 0) {
#pragma unroll
            for (int dblk = 0; dblk < 2; ++dblk)
#pragma unroll
                for (int r = 0; r < 16; ++r)
                    oacc[dblk][r] += mV[(g * 32 + dblk * 16 + r) * 64 + lane];
            lp += mL[g * 64 + lane];

            // epilogue: l = lp(self) + lp(partner l^32); O^T -> O via LDS
            float linv = 1.0f / (lp + __shfl_xor(lp, 32));
            unsigned short* Oe = &Ks[0][0] + g * 2048;  // 32q x 64d, chunk-swz
#pragma unroll
            for (int dblk = 0; dblk < 2; ++dblk)
#pragma unroll
                for (int rq = 0; rq < 4; ++rq) {
                    // d = dblk*32 + rq*8 + hi*4 + (0..3), q = l31
                    unsigned plo = cvt_pk_bf16(oacc[dblk][rq * 4 + 0] * linv,
                                               oacc[dblk][rq * 4 + 1] * linv);
                    unsigned phi = cvt_pk_bf16(oacc[dblk][rq * 4 + 2] * linv,
                                               oacc[dblk][rq * 4 + 3] * linv);
                    uint2v wv;
                    wv[0] = plo; wv[1] = phi;
                    int e = l31 * 64 + (((rq + 4 * dblk) ^ r7) << 3) + hi * 4;
                    *(uint2v*)&Oe[e] = wv;
                }
            // in-wave write->read; no barrier needed (private region)
#pragma unroll
            for (int i = 0; i < 4; ++i) {
                int q2 = i * 8 + (lane >> 3);
                int e = q2 * 64 + (((lane & 7) ^ (lane >> 3)) << 3);
                short8 ov = *(const short8*)&Oe[e];
                long orow = ((long)(b * S_LEN) + row_w + q2) * D_MODEL + h * HD + (lane & 7) * 8;
                *(short8*)&O[orow] = ov;
            }
        }
        __syncthreads();  // protect merge/Oe scratch from next tsel's staging
    }
#undef STAGE8
}

extern "C" void kernel_launch(void* const* d_in, const int* in_sizes, int n_in,
                              void* d_out, int out_size, void* d_ws, size_t ws_size,
                              hipStream_t stream) {
    const float* x  = (const float*)d_in[0];
    const float* wq = (const float*)d_in[n_in - 4];
    const float* wk = (const float*)d_in[n_in - 3];
    const float* wv = (const float*)d_in[n_in - 2];
    const float* wo = (const float*)d_in[n_in - 1];
    float* out = (float*)d_out;

    unsigned short* ws    = (unsigned short*)d_ws;
    unsigned short* xb    = ws;                                   // 4096 x 2048
    unsigned short* Obuf  = ws;                                   // reuses xb
    unsigned short* qkv   = xb + (long)BATCH * S_LEN * D_MODEL;   // 4096 x 3072
    unsigned short* woT   = qkv + (long)BATCH * S_LEN * QKV_N;    // 2048 x 2048
    unsigned short* wqkvT = woT + (long)D_MODEL * D_MODEL;        // 3072 x 2048
    unsigned short* Vt    = wqkvT;                                // reuses wqkvT

    const int M = BATCH * S_LEN;  // 4096

    // fused cast + weight transposes (1 launch, 18432 blocks)
    prep<<<18432, 256, 0, stream>>>(x, wq, wk, wv, wo, xb, wqkvT, woT);

    // QKV projection: 256x256 counted-vmcnt pipeline (192 blocks)
    gemm9<<<dim3(M / 256, QKV_N / 256), 512, 0, stream>>>(xb, wqkvT, qkv);

    // RoPE (all 40 heads, Q pre-scaled) + V transpose (1 launch)
    rope_vtrans<<<1024, 256, 0, stream>>>(qkv, Vt);

    flash8<<<dim3(8, NH, BATCH), 512, 0, stream>>>(qkv, Vt, Obuf);

    // out projection: 128x128 swizzled tiles (512 blocks = 2/CU, MI=4)
    gemm_sw<128, true><<<dim3(M / 128, D_MODEL / 128), 256, 0, stream>>>(
        Obuf, woT, out, M, D_MODEL, D_MODEL);
}